// Round 10
// baseline (129.078 us; speedup 1.0000x reference)
//
#include <hip/hip_runtime.h>
#include <hip/hip_bf16.h>
#include <math.h>

#define SUMS 199
#define NBLK 1024   // 16 images = 4 batch elements per block, 512 threads / 8 waves

typedef __attribute__((ext_vector_type(8))) short short8;   // 8 bf16
typedef __attribute__((ext_vector_type(4))) float float4v;  // MFMA acc

union Frag8 { short8 v; unsigned u[4]; uint4 q; };

static __device__ inline unsigned pk_bf16(float a, float b) {
    __hip_bfloat162 h = __float22bfloat162_rn(make_float2(a, b));
    union { __hip_bfloat162 h; unsigned u; } c; c.h = h; return c.u;
}
static __device__ inline unsigned short bf16_1(float a) {
    union { __hip_bfloat16 h; unsigned short u; } c;
    c.h = __float2bfloat16(a); return c.u;
}
// Cross-lane via DPP quad_perm (pure VALU; __shfl_xor = ds_bpermute on the
// LDS pipe). 0x4E = xor-2, 0xB1 = xor-1.
template <int CTRL>
static __device__ inline float fmax_xdpp(float v) {
    const int s = __builtin_amdgcn_update_dpp(0, __float_as_int(v), CTRL, 0xF, 0xF, true);
    return fmaxf(v, __int_as_float(s));
}
template <int CTRL>
static __device__ inline float add_xdpp(float v) {
    const int s = __builtin_amdgcn_update_dpp(0, __float_as_int(v), CTRL, 0xF, 0xF, true);
    return v + __int_as_float(s);
}

// ---- pre-kernel: all weight fragments -> d_ws (bf16 frag layout) ----
// c2 K-map (dense): pos = 4*s + h, ky = pos/5, kx = pos%5, valid pos < 25
// => conv2 needs only 7 K-steps (K=224).
__global__ __launch_bounds__(256) void convert_weights(
    const float* __restrict__ f1w, const float* __restrict__ f2w,
    const float* __restrict__ f3w, const float* __restrict__ c1w,
    const float* __restrict__ c2w, uint4* __restrict__ ws)
{
    const int g = blockIdx.x * 256 + threadIdx.x;
    if (g >= 6400) return;
    float v[8];
    if (g < 5824) {
        const float* W; int O, K, ld, nt, s, l;
        if (g < 4096)      { W = f1w; O = 120; K = 256; ld = 256; nt = g >> 9; s = (g >> 6) & 7; l = g & 63; }
        else if (g < 5632) { const int f = g - 4096; W = f2w; O = 84; K = 120; ld = 120; nt = f >> 8; s = (f >> 6) & 3; l = f & 63; }
        else               { const int f = g - 5632; W = f3w; O = 10; K = 84;  ld = 84;  nt = 0; s = f >> 6; l = f & 63; }
        const int o = nt * 16 + (l & 15);
        #pragma unroll
        for (int j = 0; j < 8; ++j) {
            const int k = 32 * s + 8 * (l >> 4) + j;
            v[j] = (o < O && k < K) ? W[o * ld + k] : 0.f;
        }
    } else if (g < 6336) {
        const int f = g - 5824, s = f >> 6, l = f & 63;
        const int c = l & 15, h = l >> 4;
        const int pos = 4 * s + h;           // dense position index
        const int ky = pos / 5, kx = pos % 5;
        const bool ok = (pos < 25);
        #pragma unroll
        for (int jp = 0; jp < 4; ++jp) {
            v[2 * jp]     = (ok && 2 * jp < 6)     ? c2w[c * 150 + (2 * jp) * 25 + ky * 5 + kx]     : 0.f;
            v[2 * jp + 1] = (ok && 2 * jp + 1 < 6) ? c2w[c * 150 + (2 * jp + 1) * 25 + ky * 5 + kx] : 0.f;
        }
    } else {
        const int l = (g - 6336) & 63;
        const int c = l & 15, h = l >> 4;
        const int oc = c >> 1, xs = c & 1;
        #pragma unroll
        for (int j = 0; j < 8; ++j) {
            const int p = h * 4 + (j >> 1);
            float w = 0.f;
            if (p < 15 && c < 12) {
                const int ky = p / 3, kx = 2 * (p % 3) + (j & 1) - xs;
                if (kx >= 0 && kx < 5) w = c1w[oc * 25 + ky * 5 + kx];
            }
            v[j] = w;
        }
    }
    uint4 r;
    r.x = pk_bf16(v[0], v[1]); r.y = pk_bf16(v[2], v[3]);
    r.z = pk_bf16(v[4], v[5]); r.w = pk_bf16(v[6], v[7]);
    ws[g] = r;
}

// LDS map (39680 B; 4 blocks/CU x 8 waves = 32 waves/CU, was 16):
//  [0,12672)      imgu bf16 [8 wave-slots][396 dw] (1 image/slot/pass).
//                 After convs: A2 [16][68dw]@0, A3 [16][52dw]@4352,
//                 pgf [16][12]f32 @7680, Hf/Lf [4][20]f32 @8448/@8768.
//  [12672,31232)  p1 bf16 [8 wave-slots][145 uint4], ch-6/7 dwords stay 0.
//  [31232,39680)  A1 bf16 [16 img][132 dw]
//
// R10: 512-thread blocks. Wave w owns ONE image per pass (pass*8+w) end to
// end: stage -> conv1 (N-cols (qxo,par,qyo); y-pool via DPP xor-2; stores
// bank-distinct) -> conv2 (s-outer, w2 streamed from L2). Front chains halve
// vs R8 while fc keeps full efficiency: A1 still [16 img]; fc1 = 8 waves x 1
// n-tile (o=16w+c), fc2 = 6 waves x 1 tile, tail on waves 0-3 (be = wav).
// Register budget trimmed (no pf prefetch, no w2 hoist, no conv1 dbuf) to
// fit the 64-VGPR cap of __launch_bounds__(512,8) -- the R4 spill lesson.
//
// Circuit factorization (exact regroup): n1+n2 = 10(h1+h2)+(l1+l2) =>
// P_sum = (ptens1 (*) ptens2) outer-convolved with (pones1 (*) pones2);
// H,L are 19-long convs; each of the 199 outputs needs <=2 H[b]*L[a] terms.
__global__ __launch_bounds__(512, 8) void lenet_circuit_kernel(
    const float* __restrict__ images,
    const float* __restrict__ c1b, const float* __restrict__ c2b,
    const float* __restrict__ f1b, const float* __restrict__ f2b,
    const float* __restrict__ f3b, const uint4* __restrict__ wsb,
    float* __restrict__ out)
{
    __shared__ __align__(16) unsigned char s_mem[39680];
    unsigned*       imgu = (unsigned*)s_mem;
    uint2*          imgw = (uint2*)s_mem;
    unsigned short* p1s  = (unsigned short*)(s_mem + 12672);
    const uint4*    p1u4 = (const uint4*)(s_mem + 12672);
    unsigned short* A1s  = (unsigned short*)(s_mem + 31232);
    const uint4*    A1q  = (const uint4*)(s_mem + 31232);
    float*          pgf  = (float*)(s_mem + 7680);    // [16][12] probs
    float*          Hf   = (float*)(s_mem + 8448);    // [4][20]
    float*          Lf   = (float*)(s_mem + 8768);    // [4][20]

    const int t = threadIdx.x, bid = blockIdx.x;
    const int lane = t & 63, wav = t >> 6;   // 8 waves
    const int c = lane & 15, h = lane >> 4;
    const uint4 z4 = {0u, 0u, 0u, 0u};

    // conv1 column decomposition: c = (qxo<<2) | (par<<1) | qyo
    const int qxo = c >> 2, par = (c >> 1) & 1, qyo = c & 1;

    // ---- zero own p1 slot (wave-private; pad ch 6-7 must stay 0) ----
    {
        uint4* pz = (uint4*)(s_mem + 12672) + wav * 145;
        for (int j = lane; j < 145; j += 64) pz[j] = z4;
    }
    // ---- conv1 weights + index tables ----
    Frag8 a1; a1.q = wsb[6336 + lane];
    int koff[7];
    #pragma unroll
    for (int s = 0; s < 7; ++s) {
        const int pos = 4 * s + h;
        koff[s] = (pos < 25) ? (pos / 5) * 12 + (pos % 5) : 0;
    }
    int pd[4];
    #pragma unroll
    for (int q = 0; q < 4; ++q) {
        const int p = 4 * h + q;
        pd[q] = (p < 15) ? (p / 3) * 14 + (p % 3) : 0;
    }
    float bias0 = 0.f, bias1 = 0.f;
    if (h < 3) { bias0 = c1b[2 * h]; bias1 = c1b[2 * h + 1]; }
    const float b2v = c2b[c];

    // ================= two passes, wave-private, 1 image/wave/pass =========
    #pragma unroll
    for (int pass = 0; pass < 2; ++pass) {
        // ---- stage own image fp32 -> bf16 into own imgu slot ----
        {
            const float4* g = (const float4*)(images) +
                              ((size_t)bid * 16 + pass * 8 + wav) * 196;
            #pragma unroll
            for (int k = 0; k < 4; ++k) {
                const int i = lane + 64 * k;
                if (i < 196) {
                    const float4 v = g[i];
                    uint2 wv; wv.x = pk_bf16(v.x, v.y); wv.y = pk_bf16(v.z, v.w);
                    imgw[wav * 198 + i] = wv;
                }
            }
        }
        // ---- conv1: 18 MFMA over own image; pool via DPP xor-2 ----
        {
            const int imb = wav * 396 + (2 * qyo + par) * 14 + qxo;
            const int pst = wav * 1160 + 2 * h;
            for (int Q = 0; Q < 6; ++Q) {
                unsigned d[12];
                #pragma unroll
                for (int x = 0; x < 3; ++x)
                    #pragma unroll
                    for (int q = 0; q < 4; ++q)
                        d[x * 4 + q] = imgu[imb + Q * 56 + x * 4 + pd[q]];
                float4v acc[3];
                #pragma unroll
                for (int x = 0; x < 3; ++x) {
                    Frag8 bf;
                    #pragma unroll
                    for (int q = 0; q < 4; ++q) bf.u[q] = d[x * 4 + q];
                    float4v a0 = {0.f, 0.f, 0.f, 0.f};
                    acc[x] = __builtin_amdgcn_mfma_f32_16x16x32_bf16(a1.v, bf.v, a0, 0, 0, 0);
                }
                float v0[3], v1[3];
                #pragma unroll
                for (int x = 0; x < 3; ++x) {
                    v0[x] = fmax_xdpp<0x4E>(fmaxf(acc[x][0], acc[x][1]));  // xs + y-par pool
                    v1[x] = fmax_xdpp<0x4E>(fmaxf(acc[x][2], acc[x][3]));
                }
                if (par == 0 && h < 3) {
                    #pragma unroll
                    for (int x = 0; x < 3; ++x) {
                        const int qy = 2 * Q + qyo, qx = x * 4 + qxo;
                        *(unsigned*)&p1s[pst + qy * 96 + qx * 8] =
                            pk_bf16(fmaxf(v0[x] + bias0, 0.f), fmaxf(v1[x] + bias1, 0.f));
                    }
                }
            }
        }
        // ---- conv2: 28 MFMA over own p1 slot; w2 streamed (L2-hot);
        //      epilogue = per-lane b16 store to A1 ----
        {
            const int pxl = (c & 1) + 2 * ((c >> 2) & 1);
            const int pyl = ((c >> 1) & 1) + 2 * ((c >> 3) & 1);
            int pbase[4];
            #pragma unroll
            for (int mt = 0; mt < 4; ++mt)
                pbase[mt] = wav * 145 + (pyl + 4 * (mt >> 1)) * 12 + pxl + 4 * (mt & 1);
            float4v acc[4];
            #pragma unroll
            for (int mt = 0; mt < 4; ++mt) acc[mt] = (float4v){0.f, 0.f, 0.f, 0.f};
            #pragma unroll
            for (int s = 0; s < 7; ++s) {
                Frag8 wz; wz.q = wsb[5824 + s * 64 + lane];
                #pragma unroll
                for (int mt = 0; mt < 4; ++mt) {
                    Frag8 af; af.q = p1u4[pbase[mt] + koff[s]];
                    acc[mt] = __builtin_amdgcn_mfma_f32_16x16x32_bf16(af.v, wz.v, acc[mt], 0, 0, 0);
                }
            }
            const int img = pass * 8 + wav;
            #pragma unroll
            for (int mt = 0; mt < 4; ++mt) {
                const float p = fmaxf(fmaxf(acc[mt][0], acc[mt][1]),
                                      fmaxf(acc[mt][2], acc[mt][3]));
                const float ov = fmaxf(p + b2v, 0.f);
                const int qy = (h >> 1) + 2 * (mt >> 1);
                A1s[img * 264 + c * 16 + qy * 4 + 2 * (mt & 1) + (h & 1)] = bf16_1(ov);
            }
        }
    }

    // ---- prefetch fc1 B-frags s=0..3 (n-tile = wav) before the barrier ----
    Frag8 fB[4];
    #pragma unroll
    for (int s = 0; s < 4; ++s) fB[s].q = wsb[(wav * 8 + s) * 64 + lane];
    __syncthreads();     // A1 complete (16 images); imgu/p1 dead

    // ---- fc1 via MFMA: 8 waves x 1 n-tile (o = 16*wav + c) ----
    {
        unsigned* A2d = (unsigned*)s_mem;
        unsigned short* A2s = (unsigned short*)s_mem;
        if (t < 64) A2d[(t >> 2) * 68 + 60 + (t & 3)] = 0u;   // k-pad 120-127
        Frag8 gB[4];
        #pragma unroll
        for (int s = 0; s < 4; ++s) gB[s].q = wsb[(wav * 8 + 4 + s) * 64 + lane];
        Frag8 afA[4];
        #pragma unroll
        for (int s = 0; s < 4; ++s) afA[s].q = A1q[c * 33 + 4 * s + h];
        float4v acc = {0.f, 0.f, 0.f, 0.f};
        #pragma unroll
        for (int s = 0; s < 4; ++s)
            acc = __builtin_amdgcn_mfma_f32_16x16x32_bf16(afA[s].v, fB[s].v, acc, 0, 0, 0);
        #pragma unroll
        for (int s = 0; s < 4; ++s) afA[s].q = A1q[c * 33 + 4 * (4 + s) + h];
        #pragma unroll
        for (int s = 0; s < 4; ++s)
            acc = __builtin_amdgcn_mfma_f32_16x16x32_bf16(afA[s].v, gB[s].v, acc, 0, 0, 0);
        const int o = 16 * wav + c;
        if (o < 120) {
            const float bias = f1b[o];
            #pragma unroll
            for (int r = 0; r < 4; ++r)
                A2s[(4 * h + r) * 136 + o] = bf16_1(fmaxf(acc[r] + bias, 0.f));
        }
    }
    // ---- prefetch fc2 B-frags (n-tile = wav, waves 0-5) before barrier ----
    Frag8 hB[4];
    if (wav < 6) {
        #pragma unroll
        for (int s = 0; s < 4; ++s) hB[s].q = wsb[4096 + (wav * 4 + s) * 64 + lane];
    }
    __syncthreads();

    // ---- fc2 via MFMA: waves 0-5 x 1 n-tile (o = 16*wav + c) ----
    {
        unsigned* A3d = (unsigned*)(s_mem + 4352);
        unsigned short* A3s = (unsigned short*)(s_mem + 4352);
        if (t < 96) A3d[(t / 6) * 52 + 42 + (t % 6)] = 0u;    // k-pad 84-95
        if (wav < 6) {
            const uint4* A2q = (const uint4*)s_mem;
            Frag8 afA[4];
            #pragma unroll
            for (int s = 0; s < 4; ++s) afA[s].q = A2q[c * 17 + 4 * s + h];
            float4v acc = {0.f, 0.f, 0.f, 0.f};
            #pragma unroll
            for (int s = 0; s < 4; ++s)
                acc = __builtin_amdgcn_mfma_f32_16x16x32_bf16(afA[s].v, hB[s].v, acc, 0, 0, 0);
            const int o = 16 * wav + c;
            if (o < 84) {
                const float bias = f2b[o];
                #pragma unroll
                for (int r = 0; r < 4; ++r)
                    A3s[(4 * h + r) * 104 + o] = bf16_1(fmaxf(acc[r] + bias, 0.f));
            }
        }
    }
    // ---- prefetch fc3 B-frags (waves 0-3 only) before the barrier ----
    Frag8 tB[3];
    if (wav < 4) {
        #pragma unroll
        for (int s = 0; s < 3; ++s) tB[s].q = wsb[5632 + s * 64 + lane];
    }
    __syncthreads();

    // ==== per-wave tail: waves 0-3 own batch element be = wav. Redundant
    // 16-row fc3 (3 MFMA); keep rows h == wav. LDS writes row-disjoint across
    // waves; intra-wave ordering via lgkmcnt. No barriers. Waves 4-7 exit.
    if (wav < 4) {
        const uint4* A3q = (const uint4*)(s_mem + 4352);
        Frag8 afA[3];
        #pragma unroll
        for (int s = 0; s < 3; ++s) afA[s].q = A3q[c * 13 + 4 * s + h];
        float4v acc = {0.f, 0.f, 0.f, 0.f};
        #pragma unroll
        for (int s = 0; s < 3; ++s)
            acc = __builtin_amdgcn_mfma_f32_16x16x32_bf16(afA[s].v, tB[s].v, acc, 0, 0, 0);
        const float bias = (c < 10) ? f3b[c] : 0.f;
        float x[4], m[4], e[4], sm[4];
        #pragma unroll
        for (int r = 0; r < 4; ++r) {
            x[r] = (c < 10) ? (acc[r] + bias) : -INFINITY;
            m[r] = x[r];
        }
        #pragma unroll
        for (int r = 0; r < 4; ++r) m[r] = fmax_xdpp<0xB1>(m[r]);   // xor 1 (DPP)
        #pragma unroll
        for (int r = 0; r < 4; ++r) m[r] = fmax_xdpp<0x4E>(m[r]);   // xor 2 (DPP)
        #pragma unroll
        for (int d = 4; d <= 8; d <<= 1)
            #pragma unroll
            for (int r = 0; r < 4; ++r) m[r] = fmaxf(m[r], __shfl_xor(m[r], d));
        #pragma unroll
        for (int r = 0; r < 4; ++r) { e[r] = (c < 10) ? __expf(x[r] - m[r]) : 0.f; sm[r] = e[r]; }
        #pragma unroll
        for (int r = 0; r < 4; ++r) sm[r] = add_xdpp<0xB1>(sm[r]);  // xor 1 (DPP)
        #pragma unroll
        for (int r = 0; r < 4; ++r) sm[r] = add_xdpp<0x4E>(sm[r]);  // xor 2 (DPP)
        #pragma unroll
        for (int d = 4; d <= 8; d <<= 1)
            #pragma unroll
            for (int r = 0; r < 4; ++r) sm[r] += __shfl_xor(sm[r], d);
        if (c < 10 && h == wav) {
            #pragma unroll
            for (int r = 0; r < 4; ++r)
                pgf[(4 * wav + r) * 12 + c] = e[r] / sm[r];
        }

        // ---- digit-sum convolutions for be = wav ----
        if (lane < 38) {
            const int isH = (lane < 19), b = isH ? lane : lane - 19;
            const float* pg = pgf + 4 * wav * 12;
            const float* PA = pg + (isH ? 0 : 12);    // digit 0 / 1
            const float* PB = pg + (isH ? 24 : 36);   // digit 2 / 3
            const int ilo = (b > 9) ? b - 9 : 0;
            const int ihi = (b < 9) ? b : 9;
            float s = 0.f;
            for (int i = ilo; i <= ihi; ++i) s += PA[i] * PB[b - i];
            (isH ? Hf : Lf)[wav * 20 + b] = s;
        }

        // ---- outputs for be = wav: P_sum(s) = sum H[b]*L[s-10b] (<=2 terms) ----
        const float* H = Hf + wav * 20;
        const float* L = Lf + wav * 20;
        for (int s = lane; s < SUMS; s += 64) {
            const int bmin = (s > 18) ? (s - 9) / 10 : 0;
            int bmax = s / 10; if (bmax > 18) bmax = 18;
            float sum = 0.f;
            for (int b = bmin; b <= bmax; ++b) sum += H[b] * L[s - 10 * b];
            out[((size_t)bid * 4 + wav) * SUMS + s] = __logf(sum);
        }
    }
}

extern "C" void kernel_launch(void* const* d_in, const int* in_sizes, int n_in,
                              void* d_out, int out_size, void* d_ws, size_t ws_size,
                              hipStream_t stream) {
    const float* images = (const float*)d_in[0];
    const float* c1w = (const float*)d_in[1];
    const float* c1b = (const float*)d_in[2];
    const float* c2w = (const float*)d_in[3];
    const float* c2b = (const float*)d_in[4];
    const float* f1w = (const float*)d_in[5];
    const float* f1b = (const float*)d_in[6];
    const float* f2w = (const float*)d_in[7];
    const float* f2b = (const float*)d_in[8];
    const float* f3w = (const float*)d_in[9];
    const float* f3b = (const float*)d_in[10];
    float* out = (float*)d_out;

    convert_weights<<<25, 256, 0, stream>>>(f1w, f2w, f3w, c1w, c2w, (uint4*)d_ws);
    lenet_circuit_kernel<<<NBLK, 512, 0, stream>>>(
        images, c1b, c2b, f1b, f2b, f3b, (const uint4*)d_ws, out);
}

// Round 11
// 126.058 us; speedup vs baseline: 1.0240x; 1.0240x over previous
//
#include <hip/hip_runtime.h>
#include <hip/hip_bf16.h>
#include <math.h>

#define SUMS 199
#define NBLK 1024   // 16 images = 4 batch elements per block, 512 threads / 8 waves

typedef __attribute__((ext_vector_type(8))) short short8;   // 8 bf16
typedef __attribute__((ext_vector_type(4))) float float4v;  // MFMA acc

union Frag8 { short8 v; unsigned u[4]; uint4 q; };

static __device__ inline unsigned pk_bf16(float a, float b) {
    __hip_bfloat162 h = __float22bfloat162_rn(make_float2(a, b));
    union { __hip_bfloat162 h; unsigned u; } c; c.h = h; return c.u;
}
static __device__ inline unsigned short bf16_1(float a) {
    union { __hip_bfloat16 h; unsigned short u; } c;
    c.h = __float2bfloat16(a); return c.u;
}
// Cross-lane via DPP quad_perm (pure VALU; __shfl_xor = ds_bpermute on the
// LDS pipe). 0x4E = xor-2, 0xB1 = xor-1.
template <int CTRL>
static __device__ inline float fmax_xdpp(float v) {
    const int s = __builtin_amdgcn_update_dpp(0, __float_as_int(v), CTRL, 0xF, 0xF, true);
    return fmaxf(v, __int_as_float(s));
}
template <int CTRL>
static __device__ inline float add_xdpp(float v) {
    const int s = __builtin_amdgcn_update_dpp(0, __float_as_int(v), CTRL, 0xF, 0xF, true);
    return v + __int_as_float(s);
}

// ---- pre-kernel: all weight fragments -> d_ws (bf16 frag layout) ----
// c2 K-map (dense): pos = 4*s + h, ky = pos/5, kx = pos%5, valid pos < 25
// => conv2 needs only 7 K-steps (K=224).
__global__ __launch_bounds__(256) void convert_weights(
    const float* __restrict__ f1w, const float* __restrict__ f2w,
    const float* __restrict__ f3w, const float* __restrict__ c1w,
    const float* __restrict__ c2w, uint4* __restrict__ ws)
{
    const int g = blockIdx.x * 256 + threadIdx.x;
    if (g >= 6400) return;
    float v[8];
    if (g < 5824) {
        const float* W; int O, K, ld, nt, s, l;
        if (g < 4096)      { W = f1w; O = 120; K = 256; ld = 256; nt = g >> 9; s = (g >> 6) & 7; l = g & 63; }
        else if (g < 5632) { const int f = g - 4096; W = f2w; O = 84; K = 120; ld = 120; nt = f >> 8; s = (f >> 6) & 3; l = f & 63; }
        else               { const int f = g - 5632; W = f3w; O = 10; K = 84;  ld = 84;  nt = 0; s = f >> 6; l = f & 63; }
        const int o = nt * 16 + (l & 15);
        #pragma unroll
        for (int j = 0; j < 8; ++j) {
            const int k = 32 * s + 8 * (l >> 4) + j;
            v[j] = (o < O && k < K) ? W[o * ld + k] : 0.f;
        }
    } else if (g < 6336) {
        const int f = g - 5824, s = f >> 6, l = f & 63;
        const int c = l & 15, h = l >> 4;
        const int pos = 4 * s + h;           // dense position index
        const int ky = pos / 5, kx = pos % 5;
        const bool ok = (pos < 25);
        #pragma unroll
        for (int jp = 0; jp < 4; ++jp) {
            v[2 * jp]     = (ok && 2 * jp < 6)     ? c2w[c * 150 + (2 * jp) * 25 + ky * 5 + kx]     : 0.f;
            v[2 * jp + 1] = (ok && 2 * jp + 1 < 6) ? c2w[c * 150 + (2 * jp + 1) * 25 + ky * 5 + kx] : 0.f;
        }
    } else {
        const int l = (g - 6336) & 63;
        const int c = l & 15, h = l >> 4;
        const int oc = c >> 1, xs = c & 1;
        #pragma unroll
        for (int j = 0; j < 8; ++j) {
            const int p = h * 4 + (j >> 1);
            float w = 0.f;
            if (p < 15 && c < 12) {
                const int ky = p / 3, kx = 2 * (p % 3) + (j & 1) - xs;
                if (kx >= 0 && kx < 5) w = c1w[oc * 25 + ky * 5 + kx];
            }
            v[j] = w;
        }
    }
    uint4 r;
    r.x = pk_bf16(v[0], v[1]); r.y = pk_bf16(v[2], v[3]);
    r.z = pk_bf16(v[4], v[5]); r.w = pk_bf16(v[6], v[7]);
    ws[g] = r;
}

// LDS map (39680 B; 4 blocks/CU x 8 waves = 32 waves/CU):
//  [0,12672)      imgu bf16 [8 wave-slots][396 dw] (1 image/slot/pass).
//                 After convs: A2 [16][68dw]@0, A3 [16][52dw]@4352,
//                 pgf [16][12]f32 @7680, Hf/Lf [4][20]f32 @8448/@8768.
//  [12672,31232)  p1 bf16 [8 wave-slots][145 uint4], ch-6/7 dwords stay 0.
//  [31232,39680)  A1 bf16 [16 img][132 dw]
//
// R10 structure: 512-thread blocks, wave w owns ONE image per pass end to
// end (stage -> conv1 (N-cols (qxo,par,qyo), DPP pool) -> conv2 (s-outer,
// w2 streamed)); fc1 = 8 waves x 1 n-tile, fc2 = 6 waves, tail waves 0-3.
//
// R11: no cross-barrier register state. R10 spilled ~7 dwords/thread
// (WRITE_SIZE 3.2->17.5 MB) because fB/hB/tB prefetches were held live
// across __syncthreads under the 64-VGPR cap. All fc B-fragments now load
// inside their s-loops -- 8-wave TLP hides the L2 latency (the premise of
// this structure), registers stay < 64, no scratch.
//
// Circuit factorization (exact regroup): n1+n2 = 10(h1+h2)+(l1+l2) =>
// P_sum = (ptens1 (*) ptens2) outer-convolved with (pones1 (*) pones2);
// H,L are 19-long convs; each of the 199 outputs needs <=2 H[b]*L[a] terms.
__global__ __launch_bounds__(512, 8) void lenet_circuit_kernel(
    const float* __restrict__ images,
    const float* __restrict__ c1b, const float* __restrict__ c2b,
    const float* __restrict__ f1b, const float* __restrict__ f2b,
    const float* __restrict__ f3b, const uint4* __restrict__ wsb,
    float* __restrict__ out)
{
    __shared__ __align__(16) unsigned char s_mem[39680];
    unsigned*       imgu = (unsigned*)s_mem;
    uint2*          imgw = (uint2*)s_mem;
    unsigned short* p1s  = (unsigned short*)(s_mem + 12672);
    const uint4*    p1u4 = (const uint4*)(s_mem + 12672);
    unsigned short* A1s  = (unsigned short*)(s_mem + 31232);
    const uint4*    A1q  = (const uint4*)(s_mem + 31232);
    float*          pgf  = (float*)(s_mem + 7680);    // [16][12] probs
    float*          Hf   = (float*)(s_mem + 8448);    // [4][20]
    float*          Lf   = (float*)(s_mem + 8768);    // [4][20]

    const int t = threadIdx.x, bid = blockIdx.x;
    const int lane = t & 63, wav = t >> 6;   // 8 waves
    const int c = lane & 15, h = lane >> 4;
    const uint4 z4 = {0u, 0u, 0u, 0u};

    // conv1 column decomposition: c = (qxo<<2) | (par<<1) | qyo
    const int qxo = c >> 2, par = (c >> 1) & 1, qyo = c & 1;

    // ---- zero own p1 slot (wave-private; pad ch 6-7 must stay 0) ----
    {
        uint4* pz = (uint4*)(s_mem + 12672) + wav * 145;
        for (int j = lane; j < 145; j += 64) pz[j] = z4;
    }
    // ---- conv1 weights + index tables ----
    Frag8 a1; a1.q = wsb[6336 + lane];
    int koff[7];
    #pragma unroll
    for (int s = 0; s < 7; ++s) {
        const int pos = 4 * s + h;
        koff[s] = (pos < 25) ? (pos / 5) * 12 + (pos % 5) : 0;
    }
    int pd[4];
    #pragma unroll
    for (int q = 0; q < 4; ++q) {
        const int p = 4 * h + q;
        pd[q] = (p < 15) ? (p / 3) * 14 + (p % 3) : 0;
    }
    float bias0 = 0.f, bias1 = 0.f;
    if (h < 3) { bias0 = c1b[2 * h]; bias1 = c1b[2 * h + 1]; }
    const float b2v = c2b[c];

    // ================= two passes, wave-private, 1 image/wave/pass =========
    #pragma unroll
    for (int pass = 0; pass < 2; ++pass) {
        // ---- stage own image fp32 -> bf16 into own imgu slot ----
        {
            const float4* g = (const float4*)(images) +
                              ((size_t)bid * 16 + pass * 8 + wav) * 196;
            #pragma unroll
            for (int k = 0; k < 4; ++k) {
                const int i = lane + 64 * k;
                if (i < 196) {
                    const float4 v = g[i];
                    uint2 wv; wv.x = pk_bf16(v.x, v.y); wv.y = pk_bf16(v.z, v.w);
                    imgw[wav * 198 + i] = wv;
                }
            }
        }
        // ---- conv1: 18 MFMA over own image; pool via DPP xor-2 ----
        {
            const int imb = wav * 396 + (2 * qyo + par) * 14 + qxo;
            const int pst = wav * 1160 + 2 * h;
            for (int Q = 0; Q < 6; ++Q) {
                unsigned d[12];
                #pragma unroll
                for (int x = 0; x < 3; ++x)
                    #pragma unroll
                    for (int q = 0; q < 4; ++q)
                        d[x * 4 + q] = imgu[imb + Q * 56 + x * 4 + pd[q]];
                float4v acc[3];
                #pragma unroll
                for (int x = 0; x < 3; ++x) {
                    Frag8 bf;
                    #pragma unroll
                    for (int q = 0; q < 4; ++q) bf.u[q] = d[x * 4 + q];
                    float4v a0 = {0.f, 0.f, 0.f, 0.f};
                    acc[x] = __builtin_amdgcn_mfma_f32_16x16x32_bf16(a1.v, bf.v, a0, 0, 0, 0);
                }
                float v0[3], v1[3];
                #pragma unroll
                for (int x = 0; x < 3; ++x) {
                    v0[x] = fmax_xdpp<0x4E>(fmaxf(acc[x][0], acc[x][1]));  // xs + y-par pool
                    v1[x] = fmax_xdpp<0x4E>(fmaxf(acc[x][2], acc[x][3]));
                }
                if (par == 0 && h < 3) {
                    #pragma unroll
                    for (int x = 0; x < 3; ++x) {
                        const int qy = 2 * Q + qyo, qx = x * 4 + qxo;
                        *(unsigned*)&p1s[pst + qy * 96 + qx * 8] =
                            pk_bf16(fmaxf(v0[x] + bias0, 0.f), fmaxf(v1[x] + bias1, 0.f));
                    }
                }
            }
        }
        // ---- conv2: 28 MFMA over own p1 slot; w2 streamed (L2-hot);
        //      epilogue = per-lane b16 store to A1 ----
        {
            const int pxl = (c & 1) + 2 * ((c >> 2) & 1);
            const int pyl = ((c >> 1) & 1) + 2 * ((c >> 3) & 1);
            int pbase[4];
            #pragma unroll
            for (int mt = 0; mt < 4; ++mt)
                pbase[mt] = wav * 145 + (pyl + 4 * (mt >> 1)) * 12 + pxl + 4 * (mt & 1);
            float4v acc[4];
            #pragma unroll
            for (int mt = 0; mt < 4; ++mt) acc[mt] = (float4v){0.f, 0.f, 0.f, 0.f};
            #pragma unroll
            for (int s = 0; s < 7; ++s) {
                Frag8 wz; wz.q = wsb[5824 + s * 64 + lane];
                #pragma unroll
                for (int mt = 0; mt < 4; ++mt) {
                    Frag8 af; af.q = p1u4[pbase[mt] + koff[s]];
                    acc[mt] = __builtin_amdgcn_mfma_f32_16x16x32_bf16(af.v, wz.v, acc[mt], 0, 0, 0);
                }
            }
            const int img = pass * 8 + wav;
            #pragma unroll
            for (int mt = 0; mt < 4; ++mt) {
                const float p = fmaxf(fmaxf(acc[mt][0], acc[mt][1]),
                                      fmaxf(acc[mt][2], acc[mt][3]));
                const float ov = fmaxf(p + b2v, 0.f);
                const int qy = (h >> 1) + 2 * (mt >> 1);
                A1s[img * 264 + c * 16 + qy * 4 + 2 * (mt & 1) + (h & 1)] = bf16_1(ov);
            }
        }
    }
    __syncthreads();     // A1 complete (16 images); imgu/p1 dead

    // ---- fc1 via MFMA: 8 waves x 1 n-tile (o = 16*wav + c); B loaded
    //      inside the s-loop (no cross-barrier register state) ----
    {
        unsigned* A2d = (unsigned*)s_mem;
        unsigned short* A2s = (unsigned short*)s_mem;
        if (t < 64) A2d[(t >> 2) * 68 + 60 + (t & 3)] = 0u;   // k-pad 120-127
        float4v acc = {0.f, 0.f, 0.f, 0.f};
        #pragma unroll
        for (int s = 0; s < 8; ++s) {
            Frag8 b;  b.q  = wsb[(wav * 8 + s) * 64 + lane];
            Frag8 af; af.q = A1q[c * 33 + 4 * s + h];
            acc = __builtin_amdgcn_mfma_f32_16x16x32_bf16(af.v, b.v, acc, 0, 0, 0);
        }
        const int o = 16 * wav + c;
        if (o < 120) {
            const float bias = f1b[o];
            #pragma unroll
            for (int r = 0; r < 4; ++r)
                A2s[(4 * h + r) * 136 + o] = bf16_1(fmaxf(acc[r] + bias, 0.f));
        }
    }
    __syncthreads();

    // ---- fc2 via MFMA: waves 0-5 x 1 n-tile (o = 16*wav + c) ----
    {
        unsigned* A3d = (unsigned*)(s_mem + 4352);
        unsigned short* A3s = (unsigned short*)(s_mem + 4352);
        if (t < 96) A3d[(t / 6) * 52 + 42 + (t % 6)] = 0u;    // k-pad 84-95
        if (wav < 6) {
            const uint4* A2q = (const uint4*)s_mem;
            float4v acc = {0.f, 0.f, 0.f, 0.f};
            #pragma unroll
            for (int s = 0; s < 4; ++s) {
                Frag8 b;  b.q  = wsb[4096 + (wav * 4 + s) * 64 + lane];
                Frag8 af; af.q = A2q[c * 17 + 4 * s + h];
                acc = __builtin_amdgcn_mfma_f32_16x16x32_bf16(af.v, b.v, acc, 0, 0, 0);
            }
            const int o = 16 * wav + c;
            if (o < 84) {
                const float bias = f2b[o];
                #pragma unroll
                for (int r = 0; r < 4; ++r)
                    A3s[(4 * h + r) * 104 + o] = bf16_1(fmaxf(acc[r] + bias, 0.f));
            }
        }
    }
    __syncthreads();

    // ==== per-wave tail: waves 0-3 own batch element be = wav. Redundant
    // 16-row fc3 (3 MFMA); keep rows h == wav. LDS writes row-disjoint across
    // waves; intra-wave ordering via lgkmcnt. No barriers. Waves 4-7 exit.
    if (wav < 4) {
        const uint4* A3q = (const uint4*)(s_mem + 4352);
        float4v acc = {0.f, 0.f, 0.f, 0.f};
        #pragma unroll
        for (int s = 0; s < 3; ++s) {
            Frag8 b;  b.q  = wsb[5632 + s * 64 + lane];
            Frag8 af; af.q = A3q[c * 13 + 4 * s + h];
            acc = __builtin_amdgcn_mfma_f32_16x16x32_bf16(af.v, b.v, acc, 0, 0, 0);
        }
        const float bias = (c < 10) ? f3b[c] : 0.f;
        float x[4], m[4], e[4], sm[4];
        #pragma unroll
        for (int r = 0; r < 4; ++r) {
            x[r] = (c < 10) ? (acc[r] + bias) : -INFINITY;
            m[r] = x[r];
        }
        #pragma unroll
        for (int r = 0; r < 4; ++r) m[r] = fmax_xdpp<0xB1>(m[r]);   // xor 1 (DPP)
        #pragma unroll
        for (int r = 0; r < 4; ++r) m[r] = fmax_xdpp<0x4E>(m[r]);   // xor 2 (DPP)
        #pragma unroll
        for (int d = 4; d <= 8; d <<= 1)
            #pragma unroll
            for (int r = 0; r < 4; ++r) m[r] = fmaxf(m[r], __shfl_xor(m[r], d));
        #pragma unroll
        for (int r = 0; r < 4; ++r) { e[r] = (c < 10) ? __expf(x[r] - m[r]) : 0.f; sm[r] = e[r]; }
        #pragma unroll
        for (int r = 0; r < 4; ++r) sm[r] = add_xdpp<0xB1>(sm[r]);  // xor 1 (DPP)
        #pragma unroll
        for (int r = 0; r < 4; ++r) sm[r] = add_xdpp<0x4E>(sm[r]);  // xor 2 (DPP)
        #pragma unroll
        for (int d = 4; d <= 8; d <<= 1)
            #pragma unroll
            for (int r = 0; r < 4; ++r) sm[r] += __shfl_xor(sm[r], d);
        if (c < 10 && h == wav) {
            #pragma unroll
            for (int r = 0; r < 4; ++r)
                pgf[(4 * wav + r) * 12 + c] = e[r] / sm[r];
        }

        // ---- digit-sum convolutions for be = wav ----
        if (lane < 38) {
            const int isH = (lane < 19), b = isH ? lane : lane - 19;
            const float* pg = pgf + 4 * wav * 12;
            const float* PA = pg + (isH ? 0 : 12);    // digit 0 / 1
            const float* PB = pg + (isH ? 24 : 36);   // digit 2 / 3
            const int ilo = (b > 9) ? b - 9 : 0;
            const int ihi = (b < 9) ? b : 9;
            float s = 0.f;
            for (int i = ilo; i <= ihi; ++i) s += PA[i] * PB[b - i];
            (isH ? Hf : Lf)[wav * 20 + b] = s;
        }

        // ---- outputs for be = wav: P_sum(s) = sum H[b]*L[s-10b] (<=2 terms) ----
        const float* H = Hf + wav * 20;
        const float* L = Lf + wav * 20;
        for (int s = lane; s < SUMS; s += 64) {
            const int bmin = (s > 18) ? (s - 9) / 10 : 0;
            int bmax = s / 10; if (bmax > 18) bmax = 18;
            float sum = 0.f;
            for (int b = bmin; b <= bmax; ++b) sum += H[b] * L[s - 10 * b];
            out[((size_t)bid * 4 + wav) * SUMS + s] = __logf(sum);
        }
    }
}

extern "C" void kernel_launch(void* const* d_in, const int* in_sizes, int n_in,
                              void* d_out, int out_size, void* d_ws, size_t ws_size,
                              hipStream_t stream) {
    const float* images = (const float*)d_in[0];
    const float* c1w = (const float*)d_in[1];
    const float* c1b = (const float*)d_in[2];
    const float* c2w = (const float*)d_in[3];
    const float* c2b = (const float*)d_in[4];
    const float* f1w = (const float*)d_in[5];
    const float* f1b = (const float*)d_in[6];
    const float* f2w = (const float*)d_in[7];
    const float* f2b = (const float*)d_in[8];
    const float* f3w = (const float*)d_in[9];
    const float* f3b = (const float*)d_in[10];
    float* out = (float*)d_out;

    convert_weights<<<25, 256, 0, stream>>>(f1w, f2w, f3w, c1w, c2w, (uint4*)d_ws);
    lenet_circuit_kernel<<<NBLK, 512, 0, stream>>>(
        images, c1b, c2b, f1b, f2b, f3b, (const uint4*)d_ws, out);
}